// Round 14
// baseline (458.649 us; speedup 1.0000x reference)
//
#include <hip/hip_runtime.h>
#include <stdint.h>

#define T_STEPS 512
#define BATCH   128
#define N_IN    256
#define N_H     1024
#define N_OUT   32

typedef __attribute__((ext_vector_type(2))) float f32x2;

// Workspace layout, GLB mode (needs 22,286,336 B):
//   pm    u32[65536][32]  @ 0          8,388,608  (main idx, pre-mult <<8)
//   pt    u16[65536][32]  @ 8388608    4,194,304  (tail idx, raw)
//   cnts  u32[65536]      @ 12582912     262,144
//   w_t   f32[257][1024]  @ 12845056   1,052,672  (row 256 = ZERO page: glb sentinel)
//   zmask u32[65536][32]  @ 13897728   8,388,608
// Fallback (ws < needed): r13 layout (w_t 256 rows, zmask @ 13893632), GLB=0.
#define WS_GLB_NEEDED 22286336u

// ---------------- Kernel A: compact spike indices, WAVE-PER-ROW (r12, verified) ----------------
__global__ __launch_bounds__(256) void k_prep(const float* __restrict__ spikes,
                                              uint32_t* __restrict__ pm,
                                              uint16_t* __restrict__ pt,
                                              uint32_t* __restrict__ cnts) {
    __shared__ uint16_t list[4][64];              // per-wave scratch, 512 B
    const int tid = threadIdx.x;
    const int w = tid >> 6, l = tid & 63;
    uint16_t* ls = list[w];
    const int row0 = blockIdx.x * 16 + w * 4;     // wave w -> rows row0..row0+3

    for (int r = 0; r < 4; ++r) {
        const int row = row0 + r;                 // t*BATCH + b
        ls[l] = 256;                              // sentinel init (64 slots)
        __builtin_amdgcn_wave_barrier();

        const float* sp = spikes + (size_t)row * N_IN;
        float s0 = sp[l], s1 = sp[l + 64], s2 = sp[l + 128], s3 = sp[l + 192];
        unsigned long long m0 = __ballot(s0 > 0.5f);
        unsigned long long m1 = __ballot(s1 > 0.5f);
        unsigned long long m2 = __ballot(s2 > 0.5f);
        unsigned long long m3 = __ballot(s3 > 0.5f);
        const unsigned long long low = (1ull << l) - 1ull;
        uint32_t c0 = (uint32_t)__popcll(m0);
        uint32_t c1 = (uint32_t)__popcll(m1);
        uint32_t c2 = (uint32_t)__popcll(m2);
        uint32_t c3 = (uint32_t)__popcll(m3);

        // compaction: index = 64q + l, ascending (q, l) == old (wave, lane)
        if (s0 > 0.5f) {
            uint32_t pos = (uint32_t)__popcll(m0 & low);
            if (pos < 64) ls[pos] = (uint16_t)l;
        }
        if (s1 > 0.5f) {
            uint32_t pos = c0 + (uint32_t)__popcll(m1 & low);
            if (pos < 64) ls[pos] = (uint16_t)(64 + l);
        }
        if (s2 > 0.5f) {
            uint32_t pos = c0 + c1 + (uint32_t)__popcll(m2 & low);
            if (pos < 64) ls[pos] = (uint16_t)(128 + l);
        }
        if (s3 > 0.5f) {
            uint32_t pos = c0 + c1 + c2 + (uint32_t)__popcll(m3 & low);
            if (pos < 64) ls[pos] = (uint16_t)(192 + l);
        }
        __builtin_amdgcn_wave_barrier();

        // emit: same slot->list-position maps as all prior rounds
        if (l < 32) {                             // main: u32 byte offsets (<<8)
            int p = 2 * (l & 15) + (l >> 4);
            pm[(uint32_t)row * 32 + l] = ((uint32_t)ls[p]) << 8;
        } else {                                  // tail: raw u16
            int u = l - 32;
            int p = 32 + 2 * (u & 15) + (u >> 4);
            pt[(uint32_t)row * 32 + u] = ls[p];
        }
        uint32_t total = c0 + c1 + c2 + c3;
        if (l == 0) cnts[row] = total < 64u ? total : 64u;
        __builtin_amdgcn_wave_barrier();
    }
}

// ---------------- Kernel T: transpose w_h -> w_t, plus zero page (row 256) ----------------
// gid < 262144: w_t[i][h] = w_h[h][i]. gid in [262144, 263168): zero the
// sentinel row used by the k_lif global-gather path. (In the fallback layout
// this zeroes the first 4 KB of zmask - harmless: k_lif fully overwrites
// zmask before k_li reads it.)
__global__ __launch_bounds__(256) void k_tr(const float* __restrict__ w_h,
                                            float* __restrict__ w_t) {
    int gid = blockIdx.x * 256 + threadIdx.x;
    if (gid < N_H * N_IN) {
        int h = gid >> 8, i = gid & 255;
        w_t[(size_t)i * N_H + h] = w_h[gid];
    } else if (gid < N_H * N_IN + 1024) {
        w_t[(size_t)256 * N_H + (gid - N_H * N_IN)] = 0.0f;
    }
}

// permlane32_swap-based cross-half sum: after swap(a,b) with a=b=x, the pair
// {a[l],b[l]} = {x[l], x[l^32]}; a+b = x[l] + x[l^32] on every lane. Pure
// VALU, bit-identical to x + __shfl_xor(x,32) (FP add commutes).
__device__ __forceinline__ float xadd32(float x) {
    float a = x, b = x;
    asm("v_permlane32_swap_b32 %0, %1" : "+v"(a), "+v"(b));
    return a + b;
}

// Partner fetch, SEMANTICS-PROOF (r8 post-mortem): (a != x) ? a : b ==
// x[l^32] exactly under either permlane operand convention.
__device__ __forceinline__ float xpick(float x) {
    float a = x, b = x;
    asm("v_permlane32_swap_b32 %0, %1" : "+v"(a), "+v"(b));
    return (a != x) ? a : b;
}

struct IdxSet { uint4 a, b, c, d; };   // 16 u32 byte-offsets (this lane-half)

// ---------------- Kernel 12: fused sparse synapse + LIF scan, DUAL-PIPE ----------------
// Round-25: k_lif is LDS-BYTES-bound (64 KB/t/CU / 85 B/cyc = 770 cyc floor,
// measured 1010 = 76%; width/occupancy/VALU levers all measured-closed
// r4/r5/r11). The vector-memory pipe to L2 (~56 B/cyc/CU; w_t is L2-resident)
// sits idle. GLB=1: main slots 12-15 gather via global_load_dwordx2 from w_t,
// ISSUED ONE BODY (~1000 cyc) AHEAD, results added IN SLOT ORDER (after
// slots 0-11, before tail) -> values and accumulation order bit-identical
// (glb sentinel hits the zeroed w_t row 256 = +0.0f, same as LDS sentinel).
// LDS bytes/t drop 25%. GLB=0: exact r9/r13 kernel (fallback).
template<int GLB>
__global__ __launch_bounds__(256) void k_lif(const uint32_t* __restrict__ pm,
                                             const uint16_t* __restrict__ pt,
                                             const uint32_t* __restrict__ cnts,
                                             const float* __restrict__ w_t,
                                             uint32_t* __restrict__ zmask) {
    extern __shared__ __align__(16) float wl[];   // 257*64 floats = 65,792 B
    const int bg = blockIdx.x >> 4, tile = blockIdx.x & 15;
    const int h0 = tile * 64, tid = threadIdx.x;

    #pragma unroll 8
    for (int k = 0; k < 16; ++k) {                // 256 rows x 16 float4 = 4096
        int idx = (k << 8) + tid;
        int i = idx >> 4, c4 = (idx & 15) << 2;
        *(float4*)(wl + i * 64 + c4) =
            *(const float4*)(w_t + (size_t)i * N_H + h0 + c4);
    }
    if (tid < 64) wl[256 * 64 + tid] = 0.0f;      // sentinel row
    __syncthreads();

    const int wv = __builtin_amdgcn_readfirstlane(tid >> 6);  // uniform wave id 0..3
    const int b  = (bg << 2) + wv;                // one b per wave, uniform
    const int l  = tid & 63;
    const int duo2 = (l & 31) << 1;               // float offset of h-duo
    const int half16 = (l >> 5) << 4;             // u16 units: lane-half group
    const int half32 = (l >> 5) << 4;             // u32 units: lane-half group
    const char* wlb = (const char*)wl + (duo2 << 2);  // per-lane LDS base
    // per-lane global base into w_t: + h0*4 + (l&31)*8; slot addr = + (pm<<4)
    const char* wtc = (const char*)w_t + (h0 << 2) + (duo2 << 2);

    // Opaque zero in a VGPR: keeps cnts loads in the vmcnt domain.
    int vzero;
    asm("v_mov_b32 %0, 0" : "=v"(vzero));

    uint32_t cW0, cW1, cW2, cW3;                  // counts (VGPR, lane-uniform)
    IdxSet W0, W1, W2, W3;
    f32x2 RA[4], RB[4], RC[4], RD[4];             // glb gather regs (GLB=1)

#define LOADSET(CN, S, ROW) { \
    uint32_t ro_ = (uint32_t)(ROW); \
    CN = *(cnts + ro_ + vzero); \
    const uint4* mp_ = (const uint4*)(pm + ro_ * 32u + half32); \
    S.a = mp_[0]; S.b = mp_[1]; S.c = mp_[2]; S.d = mp_[3]; }

// LDS: 4 pre-multiplied byte offsets -> ds_read_b64 + pk_add per index.
// Sentinel offset 65536 = zeroed LDS sentinel row (+0.0f).
#define GCHUNK4(G, Q) { \
    G += *(const f32x2*)(wlb + (Q).x); \
    G += *(const f32x2*)(wlb + (Q).y); \
    G += *(const f32x2*)(wlb + (Q).z); \
    G += *(const f32x2*)(wlb + (Q).w); }

// Issue the 4 global loads for slots 12-15 (S.d); pm<<4 = idx*4096 = w_t row
// byte offset; sentinel -> idx 256 -> zeroed w_t row 256 (+0.0f).
#define GISSUE(R, S) { \
    R[0] = *(const f32x2*)(wtc + ((size_t)((S).d.x << 4))); \
    R[1] = *(const f32x2*)(wtc + ((size_t)((S).d.y << 4))); \
    R[2] = *(const f32x2*)(wtc + ((size_t)((S).d.z << 4))); \
    R[3] = *(const f32x2*)(wtc + ((size_t)((S).d.w << 4))); }

// Consume glb results in slot order 12..15 (same chain position as GCHUNK4(d)).
#define GCONSUME(G, R) { G += R[0]; G += R[1]; G += R[2]; G += R[3]; }

// Main gather: slots 0-11 via LDS; slots 12-15 via LDS (GLB=0) or pre-issued
// glb regs (GLB=1). Chain order identical across modes and all prior rounds.
#define GATHER_MAIN(G, S, R) { \
    GCHUNK4(G, S.a) GCHUNK4(G, S.b) GCHUNK4(G, S.c) \
    if (GLB) { GCONSUME(G, R) } else { GCHUNK4(G, S.d) } }

// Rare (~7%) tail for cnt > 32: raw u16 slots via LDS, unchanged.
#define GTCHUNK(G, U0, U1) { \
    uint32_t ia0 = (U0) & 0xFFFFu; \
    uint32_t ia1 = (U0) >> 16; \
    uint32_t ia2 = (U1) & 0xFFFFu; \
    uint32_t ia3 = (U1) >> 16; \
    G += *(const f32x2*)(wl + ia0 * 64 + duo2); \
    G += *(const f32x2*)(wl + ia1 * 64 + duo2); \
    G += *(const f32x2*)(wl + ia2 * 64 + duo2); \
    G += *(const f32x2*)(wl + ia3 * 64 + duo2); }

#define GATHER_TAIL(G, CN, ROW) do { \
    uint32_t cs = __builtin_amdgcn_readfirstlane(CN); \
    if (cs > 32u) { \
        uint32_t ro_ = (uint32_t)(ROW); \
        const uint4* tp = (const uint4*)(pt + ro_ * 32u + half16); \
        uint4 T0 = tp[0], T1 = tp[1]; \
        GTCHUNK(G, T0.x, T0.y) \
        if (cs > 40u) GTCHUNK(G, T0.z, T0.w) \
        if (cs > 48u) GTCHUNK(G, T1.x, T1.y) \
        if (cs > 56u) GTCHUNK(G, T1.z, T1.w) \
    } } while (0)

// One LIF step: identical math/order to all prior rounds.
#define SCANSTEP(G, ROW) { \
    float c0 = xadd32(G.x); \
    float c1 = xadd32(G.y); \
    s0 = __builtin_fmaf(s0, 0.875f, c0); \
    s1 = __builtin_fmaf(s1, 0.875f, c1); \
    v0 = __builtin_fmaf(0.125f, s0 - v0, v0); \
    v1 = __builtin_fmaf(0.125f, s1 - v1, v1); \
    unsigned long long m0 = __ballot(v0 > 1.0f); \
    unsigned long long m1 = __ballot(v1 > 1.0f); \
    if (v0 > 1.0f) v0 = 0.0f; \
    if (v1 > 1.0f) v1 = 0.0f; \
    if (l == 0) { \
        uint2* zp = (uint2*)(zmask + (uint32_t)((ROW) * 32 + (tile << 1))); \
        *zp = make_uint2((uint32_t)m0, (uint32_t)m1); } }

    float v0 = 0, v1 = 0, s0 = 0, s1 = 0;
    LOADSET(cW0, W0, b);                         // idx(0)
    LOADSET(cW1, W1, BATCH + b);                 // idx(1)
    LOADSET(cW2, W2, 2 * BATCH + b);             // idx(2)
    LOADSET(cW3, W3, 3 * BATCH + b);             // idx(3)
    if (GLB) { GISSUE(RA, W0) GISSUE(RB, W1) }   // prologue issue for body1

    for (int t = 0; t < T_STEPS; t += 4) {
        const int rowA = t * BATCH + b;
        const int rowB = rowA + BATCH;
        const int rowC = rowB + BATCH;
        const int rowD = rowC + BATCH;

        // ---- body 1: steps t, t+1 from W0/W1; refill W0/W1 <- t+4, t+5 ----
        if (GLB) { GISSUE(RC, W2) GISSUE(RD, W3) }   // for body2 (~1000 cyc away)
        f32x2 ga = {0.0f, 0.0f}, gb = {0.0f, 0.0f};
        GATHER_MAIN(ga, W0, RA);
        GATHER_MAIN(gb, W1, RB);
        GATHER_TAIL(ga, cW0, rowA);
        GATHER_TAIL(gb, cW1, rowB);
        {
            int r4 = t + 4; if (r4 > T_STEPS - 1) r4 = T_STEPS - 1;
            int r5 = t + 5; if (r5 > T_STEPS - 1) r5 = T_STEPS - 1;
            LOADSET(cW0, W0, r4 * BATCH + b);
            LOADSET(cW1, W1, r5 * BATCH + b);
        }
        SCANSTEP(ga, rowA);
        SCANSTEP(gb, rowB);

        // ---- body 2: steps t+2, t+3 from W2/W3; refill W2/W3 <- t+6, t+7 ----
        if (GLB) { GISSUE(RA, W0) GISSUE(RB, W1) }   // W0/W1 just refilled: rows t+4/t+5
        f32x2 gc = {0.0f, 0.0f}, gd = {0.0f, 0.0f};
        GATHER_MAIN(gc, W2, RC);
        GATHER_MAIN(gd, W3, RD);
        GATHER_TAIL(gc, cW2, rowC);
        GATHER_TAIL(gd, cW3, rowD);
        {
            int r6 = t + 6; if (r6 > T_STEPS - 1) r6 = T_STEPS - 1;
            int r7 = t + 7; if (r7 > T_STEPS - 1) r7 = T_STEPS - 1;
            LOADSET(cW2, W2, r6 * BATCH + b);
            LOADSET(cW3, W3, r7 * BATCH + b);
        }
        SCANSTEP(gc, rowC);
        SCANSTEP(gd, rowD);
    }
#undef LOADSET
#undef GCHUNK4
#undef GISSUE
#undef GCONSUME
#undef GATHER_MAIN
#undef GTCHUNK
#undef GATHER_TAIL
#undef SCANSTEP
}

// DPP partial-sum ladder step: pure VALU (backend folds into v_add_f32_dpp).
#define DPP_TERM(X, CTRL) \
    __int_as_float(__builtin_amdgcn_update_dpp(0, __float_as_int(X), CTRL, 0xF, 0xF, true))

// ---------------- Kernel 34: output synapse + LI scan, 8-way t-split (r13) ----------------
__global__ __launch_bounds__(256) void k_li(const uint32_t* __restrict__ zmask,
                                            const float* __restrict__ w_o,
                                            float* __restrict__ out,
                                            float2* __restrict__ svbuf) {
    extern __shared__ __align__(16) float wo4[];  // 1152 slots * 16 B = 18,432 B
    const int gb  = blockIdx.x;                   // seg(8) x bquad(32) x oct(8)
    const int seg = gb >> 8;
    const int rem = gb & 255;
    const int bq  = rem >> 3;
    const int oct = rem & 7;
    const int o0  = oct << 2;
    const int tid = threadIdx.x;

    for (int lin = tid; lin < 4096; lin += 256) {
        int o = lin & 3, idx = lin >> 2;
        int h = ((idx >> 6) << 6) + ((idx & 31) << 1) + ((idx >> 5) & 1);
        wo4[((idx + (idx >> 3)) << 2) + o] = w_o[(size_t)(o0 + o) * N_H + h];
    }
    __syncthreads();

    const int b    = (bq << 2) + (tid >> 6);      // one b per wave
    const int l    = tid & 63;
    const int word = l & 31;
    const int tofs = l >> 5;                      // half A: t, half B: t+1
    const uint32_t baseoff = (uint32_t)(576 * word);   // (36*word)*16 bytes
    const char* wbase = (const char*)wo4 + baseoff;
    const int t0 = seg << 6, t1 = t0 + 64;        // 64-step segment

    float s0 = 0, s1 = 0, s2 = 0, s3 = 0;
    float v0 = 0, v1 = 0, v2 = 0, v3 = 0;

    uint32_t mcur = zmask[(uint32_t)((t0 + tofs) * BATCH + b) * 32 + word];
    for (int t = t0; t < t1; t += 2) {
        uint32_t ma = mcur;
        int tp = t + 2; if (tp >= t1) tp = t0;    // dummy prefetch on last pair
        mcur = zmask[(uint32_t)((tp + tofs) * BATCH + b) * 32 + word];

        float a0 = 0.0f, a1 = 0.0f, a2 = 0.0f, a3 = 0.0f;
        while (ma) {
            int j = __builtin_ctz(ma); ma &= ma - 1;
            const float4 wv = *(const float4*)(wbase + (((j + (j >> 3)) << 4)));
            a0 += wv.x; a1 += wv.y; a2 += wv.z; a3 += wv.w;
        }

        a0 += DPP_TERM(a0, 0x111); a1 += DPP_TERM(a1, 0x111);
        a2 += DPP_TERM(a2, 0x111); a3 += DPP_TERM(a3, 0x111);
        a0 += DPP_TERM(a0, 0x112); a1 += DPP_TERM(a1, 0x112);
        a2 += DPP_TERM(a2, 0x112); a3 += DPP_TERM(a3, 0x112);
        a0 += DPP_TERM(a0, 0x114); a1 += DPP_TERM(a1, 0x114);
        a2 += DPP_TERM(a2, 0x114); a3 += DPP_TERM(a3, 0x114);
        a0 += DPP_TERM(a0, 0x118); a1 += DPP_TERM(a1, 0x118);
        a2 += DPP_TERM(a2, 0x118); a3 += DPP_TERM(a3, 0x118);
        a0 += DPP_TERM(a0, 0x142); a1 += DPP_TERM(a1, 0x142);
        a2 += DPP_TERM(a2, 0x142); a3 += DPP_TERM(a3, 0x142);

        float b0 = xpick(a0), b1 = xpick(a1), b2 = xpick(a2), b3 = xpick(a3);

        s0 = __builtin_fmaf(s0, 0.875f, a0); v0 = __builtin_fmaf(0.125f, s0 - v0, v0);
        s1 = __builtin_fmaf(s1, 0.875f, a1); v1 = __builtin_fmaf(0.125f, s1 - v1, v1);
        s2 = __builtin_fmaf(s2, 0.875f, a2); v2 = __builtin_fmaf(0.125f, s2 - v2, v2);
        s3 = __builtin_fmaf(s3, 0.875f, a3); v3 = __builtin_fmaf(0.125f, s3 - v3, v3);
        if (l == 31)
            *(float4*)(out + (size_t)(t * BATCH + b) * 32 + o0) =
                make_float4(v0, v1, v2, v3);

        s0 = __builtin_fmaf(s0, 0.875f, b0); v0 = __builtin_fmaf(0.125f, s0 - v0, v0);
        s1 = __builtin_fmaf(s1, 0.875f, b1); v1 = __builtin_fmaf(0.125f, s1 - v1, v1);
        s2 = __builtin_fmaf(s2, 0.875f, b2); v2 = __builtin_fmaf(0.125f, s2 - v2, v2);
        s3 = __builtin_fmaf(s3, 0.875f, b3); v3 = __builtin_fmaf(0.125f, s3 - v3, v3);
        if (l == 31)
            *(float4*)(out + (size_t)((t + 1) * BATCH + b) * 32 + o0) =
                make_float4(v0, v1, v2, v3);
    }
    if (l == 31) {                        // zero-run end state of this segment
        float2* sp = svbuf + ((size_t)seg * BATCH + b) * 32 + o0;
        sp[0] = make_float2(s0, v0);
        sp[1] = make_float2(s1, v1);
        sp[2] = make_float2(s2, v2);
        sp[3] = make_float2(s3, v3);
    }
}

// ---------------- Kernel F: homogeneous LI correction for segs 1..7 (r13) ----------------
__global__ __launch_bounds__(256) void k_fix(const float2* __restrict__ svbuf,
                                             float* __restrict__ out) {
    int idx = blockIdx.x * 256 + threadIdx.x;     // 448*128*32 elements
    int o = idx & 31;
    int r = idx >> 5;
    int b = r & 127;
    int t = 64 + (r >> 7);                        // t in [64, 512)
    int seg = t >> 6;                             // 1..7
    int k = (t & 63) + 1;                         // 1..64
    const float A64 = 1.9431852e-4f;              // 0.875^64
    const float C64 = 1.5545481e-3f;              // 0.125*64*A64
    float2 S = svbuf[(size_t)b * 32 + o];         // seg-0 zero-run end state
    for (int q = 1; q < seg; ++q) {               // uniform trip count per block
        float2 z = svbuf[((size_t)q * BATCH + b) * 32 + o];
        S = make_float2(z.x + A64 * S.x, z.y + A64 * S.y + C64 * S.x);
    }
    float ak = exp2f((float)k * -0.19264508f);    // 0.875^k
    float corr = __builtin_fmaf(ak, S.y, 0.125f * (float)k * ak * S.x);
    out[(size_t)(t * BATCH + b) * 32 + o] += corr;
}

// ---------------- launch ----------------
extern "C" void kernel_launch(void* const* d_in, const int* in_sizes, int n_in,
                              void* d_out, int out_size, void* d_ws, size_t ws_size,
                              hipStream_t stream) {
    const float* spikes = (const float*)d_in[0];
    const float* w_h    = (const float*)d_in[1];
    const float* w_o    = (const float*)d_in[2];
    float* out = (float*)d_out;

    char* ws = (char*)d_ws;
    uint32_t* pm    = (uint32_t*)(ws);                 //  8,388,608
    uint16_t* pt    = (uint16_t*)(ws + 8388608);       //  4,194,304
    uint32_t* cnts  = (uint32_t*)(ws + 12582912);      //    262,144
    float*    w_t   = (float*)   (ws + 12845056);      //  1,052,672 (GLB) / 1,048,576
    float2*   svbuf = (float2*)  (ws);                 //    262,144 (reuses pm)

    const int lds12 = (256 * 64 + 64) * 4;   // 65,792 B -> 2 blocks/CU
    const int lds34 = 1152 * 16;             // 18,432 B -> 8 blocks/CU
    const bool glb = ws_size >= WS_GLB_NEEDED;
    uint32_t* zmask = (uint32_t*)(ws + (glb ? 13897728 : 13893632));

    hipFuncSetAttribute((const void*)(glb ? (const void*)k_lif<1> : (const void*)k_lif<0>),
                        hipFuncAttributeMaxDynamicSharedMemorySize, lds12);
    hipFuncSetAttribute((const void*)k_li, hipFuncAttributeMaxDynamicSharedMemorySize, lds34);

    k_prep<<<(T_STEPS * BATCH) / 16, 256, 0, stream>>>(spikes, pm, pt, cnts);
    k_tr<<<(N_H * N_IN + 1024) / 256, 256, 0, stream>>>(w_h, w_t);
    if (glb)
        k_lif<1><<<512, 256, lds12, stream>>>(pm, pt, cnts, w_t, zmask);
    else
        k_lif<0><<<512, 256, lds12, stream>>>(pm, pt, cnts, w_t, zmask);
    k_li<<<8 * 32 * 8, 256, lds34, stream>>>(zmask, w_o, out, svbuf);
    k_fix<<<(448 * BATCH * N_OUT) / 256, 256, 0, stream>>>(svbuf, out);
}

// Round 15
// 373.331 us; speedup vs baseline: 1.2285x; 1.2285x over previous
//
#include <hip/hip_runtime.h>
#include <stdint.h>

#define T_STEPS 512
#define BATCH   128
#define N_IN    256
#define N_H     1024
#define N_OUT   32

typedef __attribute__((ext_vector_type(2))) float f32x2;

// Workspace layout (22,282,240 B; capacity proven in round 4):
//   pm    u32[65536][32]  @ 0          8,388,608  (main idx, pre-mult <<8)
//   pt    u16[65536][32]  @ 8388608    4,194,304  (tail idx, raw)
//   cnts  u32[65536]      @ 12582912     262,144
//   w_t   f32[256][1024]  @ 12845056   1,048,576
//   zmask u32[65536][32]  @ 13893632   8,388,608
// r14 lesson: scattered per-lane gathers belong in LDS; the L2/TA path is
// only fast coalesced (dual-pipe GLB gather: k_lif 217 -> 312 us, reverted).

// ---------------- Kernel A: transpose prologue + compact spike indices ----------------
// Round-26: k_tr folded into k_prep (saves one launch + gap). Transpose:
// 1,048,576 threads cover the 262,144-element w_h -> w_t transpose in one
// conditional (same access pattern as the old k_tr). Stream order guarantees
// w_t completes before k_lif. Then: WAVE-PER-ROW compaction (r12, verified) -
// one wave per row, zero block barriers; ballots are wave-uniform SGPRs; each
// lane derives its compaction slot from prefix popcounts. List order
// (ascending quad q, then lane) == original (wave, lane) order -> pm/pt/cnts
// BIT-IDENTICAL to all prior rounds. 4 waves x 4 rows -> 16 rows/block.
__global__ __launch_bounds__(256) void k_prep(const float* __restrict__ spikes,
                                              const float* __restrict__ w_h,
                                              float* __restrict__ w_t,
                                              uint32_t* __restrict__ pm,
                                              uint16_t* __restrict__ pt,
                                              uint32_t* __restrict__ cnts) {
    // ---- transpose prologue (was k_tr) ----
    {
        int gid = blockIdx.x * 256 + threadIdx.x;
        if (gid < N_H * N_IN) {
            int h = gid >> 8, i = gid & 255;
            w_t[(size_t)i * N_H + h] = w_h[gid];
        }
    }

    __shared__ uint16_t list[4][64];              // per-wave scratch, 512 B
    const int tid = threadIdx.x;
    const int w = tid >> 6, l = tid & 63;
    uint16_t* ls = list[w];
    const int row0 = blockIdx.x * 16 + w * 4;     // wave w -> rows row0..row0+3

    for (int r = 0; r < 4; ++r) {
        const int row = row0 + r;                 // t*BATCH + b
        ls[l] = 256;                              // sentinel init (64 slots)
        __builtin_amdgcn_wave_barrier();

        const float* sp = spikes + (size_t)row * N_IN;
        float s0 = sp[l], s1 = sp[l + 64], s2 = sp[l + 128], s3 = sp[l + 192];
        unsigned long long m0 = __ballot(s0 > 0.5f);
        unsigned long long m1 = __ballot(s1 > 0.5f);
        unsigned long long m2 = __ballot(s2 > 0.5f);
        unsigned long long m3 = __ballot(s3 > 0.5f);
        const unsigned long long low = (1ull << l) - 1ull;
        uint32_t c0 = (uint32_t)__popcll(m0);
        uint32_t c1 = (uint32_t)__popcll(m1);
        uint32_t c2 = (uint32_t)__popcll(m2);
        uint32_t c3 = (uint32_t)__popcll(m3);

        // compaction: index = 64q + l, ascending (q, l) == old (wave, lane)
        if (s0 > 0.5f) {
            uint32_t pos = (uint32_t)__popcll(m0 & low);
            if (pos < 64) ls[pos] = (uint16_t)l;
        }
        if (s1 > 0.5f) {
            uint32_t pos = c0 + (uint32_t)__popcll(m1 & low);
            if (pos < 64) ls[pos] = (uint16_t)(64 + l);
        }
        if (s2 > 0.5f) {
            uint32_t pos = c0 + c1 + (uint32_t)__popcll(m2 & low);
            if (pos < 64) ls[pos] = (uint16_t)(128 + l);
        }
        if (s3 > 0.5f) {
            uint32_t pos = c0 + c1 + c2 + (uint32_t)__popcll(m3 & low);
            if (pos < 64) ls[pos] = (uint16_t)(192 + l);
        }
        __builtin_amdgcn_wave_barrier();

        // emit: same slot->list-position maps as all prior rounds
        if (l < 32) {                             // main: u32 byte offsets (<<8)
            int p = 2 * (l & 15) + (l >> 4);
            pm[(uint32_t)row * 32 + l] = ((uint32_t)ls[p]) << 8;
        } else {                                  // tail: raw u16
            int u = l - 32;
            int p = 32 + 2 * (u & 15) + (u >> 4);
            pt[(uint32_t)row * 32 + u] = ls[p];
        }
        uint32_t total = c0 + c1 + c2 + c3;
        if (l == 0) cnts[row] = total < 64u ? total : 64u;
        __builtin_amdgcn_wave_barrier();
    }
}

// permlane32_swap-based cross-half sum: after swap(a,b) with a=b=x, the pair
// {a[l],b[l]} = {x[l], x[l^32]}; a+b = x[l] + x[l^32] on every lane. Pure
// VALU, bit-identical to x + __shfl_xor(x,32) (FP add commutes).
__device__ __forceinline__ float xadd32(float x) {
    float a = x, b = x;
    asm("v_permlane32_swap_b32 %0, %1" : "+v"(a), "+v"(b));
    return a + b;
}

// Partner fetch, SEMANTICS-PROOF (r8 post-mortem): (a != x) ? a : b ==
// x[l^32] exactly under either permlane operand convention.
__device__ __forceinline__ float xpick(float x) {
    float a = x, b = x;
    asm("v_permlane32_swap_b32 %0, %1" : "+v"(a), "+v"(b));
    return (a != x) ? a : b;
}

struct IdxSet { uint4 a, b, c, d; };   // 16 u32 byte-offsets (this lane-half)

// ---------------- Kernel 12: fused sparse synapse + LIF scan (r9/r13 verbatim) ----------------
// At its structural floor (~217 us, confirmed by 5 independent probes: width
// r5, VALU-count r3/r4, occupancy r11, dual-pipe r14). ~76% LDS-pipe-bound;
// 8 waves/CU at 2x65.8KB LDS. Spikes bit-identical to all prior rounds.
__global__ __launch_bounds__(256) void k_lif(const uint32_t* __restrict__ pm,
                                             const uint16_t* __restrict__ pt,
                                             const uint32_t* __restrict__ cnts,
                                             const float* __restrict__ w_t,
                                             uint32_t* __restrict__ zmask) {
    extern __shared__ __align__(16) float wl[];   // 257*64 floats = 65,792 B
    const int bg = blockIdx.x >> 4, tile = blockIdx.x & 15;
    const int h0 = tile * 64, tid = threadIdx.x;

    #pragma unroll 8
    for (int k = 0; k < 16; ++k) {                // 256 rows x 16 float4 = 4096
        int idx = (k << 8) + tid;
        int i = idx >> 4, c4 = (idx & 15) << 2;
        *(float4*)(wl + i * 64 + c4) =
            *(const float4*)(w_t + (size_t)i * N_H + h0 + c4);
    }
    if (tid < 64) wl[256 * 64 + tid] = 0.0f;      // sentinel row
    __syncthreads();

    const int wv = __builtin_amdgcn_readfirstlane(tid >> 6);  // uniform wave id 0..3
    const int b  = (bg << 2) + wv;                // one b per wave, uniform
    const int l  = tid & 63;
    const int duo2 = (l & 31) << 1;               // float offset of h-duo
    const int half16 = (l >> 5) << 4;             // u16 units: lane-half group
    const int half32 = (l >> 5) << 4;             // u32 units: lane-half group
    const char* wlb = (const char*)wl + (duo2 << 2);  // per-lane LDS base

    // Opaque zero in a VGPR: keeps cnts loads in the vmcnt domain.
    int vzero;
    asm("v_mov_b32 %0, 0" : "=v"(vzero));

    uint32_t cW0, cW1, cW2, cW3;                  // counts (VGPR, lane-uniform)
    IdxSet W0, W1, W2, W3;

#define LOADSET(CN, S, ROW) { \
    uint32_t ro_ = (uint32_t)(ROW); \
    CN = *(cnts + ro_ + vzero); \
    const uint4* mp_ = (const uint4*)(pm + ro_ * 32u + half32); \
    S.a = mp_[0]; S.b = mp_[1]; S.c = mp_[2]; S.d = mp_[3]; }

// 4 pre-multiplied byte offsets -> 1 v_add + ds_read_b64 + pk_add per index.
// Sentinel offset 65536 = zeroed sentinel row (+0.0f).
#define GCHUNK4(G, Q) { \
    G += *(const f32x2*)(wlb + (Q).x); \
    G += *(const f32x2*)(wlb + (Q).y); \
    G += *(const f32x2*)(wlb + (Q).z); \
    G += *(const f32x2*)(wlb + (Q).w); }

// Unconditional 16-slot main gather (sentinel slots add +0.0f); chain order
// identical to all prior rounds.
#define GATHER_MAIN(G, S) { \
    GCHUNK4(G, S.a) GCHUNK4(G, S.b) GCHUNK4(G, S.c) GCHUNK4(G, S.d) }

// Rare (~7%) tail for cnt > 32: raw u16 slots, same guard ladder and
// accumulation order as before.
#define GTCHUNK(G, U0, U1) { \
    uint32_t ia0 = (U0) & 0xFFFFu; \
    uint32_t ia1 = (U0) >> 16; \
    uint32_t ia2 = (U1) & 0xFFFFu; \
    uint32_t ia3 = (U1) >> 16; \
    G += *(const f32x2*)(wl + ia0 * 64 + duo2); \
    G += *(const f32x2*)(wl + ia1 * 64 + duo2); \
    G += *(const f32x2*)(wl + ia2 * 64 + duo2); \
    G += *(const f32x2*)(wl + ia3 * 64 + duo2); }

#define GATHER_TAIL(G, CN, ROW) do { \
    uint32_t cs = __builtin_amdgcn_readfirstlane(CN); \
    if (cs > 32u) { \
        uint32_t ro_ = (uint32_t)(ROW); \
        const uint4* tp = (const uint4*)(pt + ro_ * 32u + half16); \
        uint4 T0 = tp[0], T1 = tp[1]; \
        GTCHUNK(G, T0.x, T0.y) \
        if (cs > 40u) GTCHUNK(G, T0.z, T0.w) \
        if (cs > 48u) GTCHUNK(G, T1.x, T1.y) \
        if (cs > 56u) GTCHUNK(G, T1.z, T1.w) \
    } } while (0)

// One LIF step: identical math/order to all prior rounds.
#define SCANSTEP(G, ROW) { \
    float c0 = xadd32(G.x); \
    float c1 = xadd32(G.y); \
    s0 = __builtin_fmaf(s0, 0.875f, c0); \
    s1 = __builtin_fmaf(s1, 0.875f, c1); \
    v0 = __builtin_fmaf(0.125f, s0 - v0, v0); \
    v1 = __builtin_fmaf(0.125f, s1 - v1, v1); \
    unsigned long long m0 = __ballot(v0 > 1.0f); \
    unsigned long long m1 = __ballot(v1 > 1.0f); \
    if (v0 > 1.0f) v0 = 0.0f; \
    if (v1 > 1.0f) v1 = 0.0f; \
    if (l == 0) { \
        uint2* zp = (uint2*)(zmask + (uint32_t)((ROW) * 32 + (tile << 1))); \
        *zp = make_uint2((uint32_t)m0, (uint32_t)m1); } }

    float v0 = 0, v1 = 0, s0 = 0, s1 = 0;
    LOADSET(cW0, W0, b);                         // idx(0)
    LOADSET(cW1, W1, BATCH + b);                 // idx(1)
    LOADSET(cW2, W2, 2 * BATCH + b);             // idx(2)
    LOADSET(cW3, W3, 3 * BATCH + b);             // idx(3)

    for (int t = 0; t < T_STEPS; t += 4) {
        const int rowA = t * BATCH + b;
        const int rowB = rowA + BATCH;
        const int rowC = rowB + BATCH;
        const int rowD = rowC + BATCH;

        // ---- body 1: steps t, t+1 from W0/W1; refill W0/W1 <- t+4, t+5 ----
        f32x2 ga = {0.0f, 0.0f}, gb = {0.0f, 0.0f};
        GATHER_MAIN(ga, W0);
        GATHER_MAIN(gb, W1);
        GATHER_TAIL(ga, cW0, rowA);
        GATHER_TAIL(gb, cW1, rowB);
        {
            int r4 = t + 4; if (r4 > T_STEPS - 1) r4 = T_STEPS - 1;
            int r5 = t + 5; if (r5 > T_STEPS - 1) r5 = T_STEPS - 1;
            LOADSET(cW0, W0, r4 * BATCH + b);
            LOADSET(cW1, W1, r5 * BATCH + b);
        }
        SCANSTEP(ga, rowA);
        SCANSTEP(gb, rowB);

        // ---- body 2: steps t+2, t+3 from W2/W3; refill W2/W3 <- t+6, t+7 ----
        f32x2 gc = {0.0f, 0.0f}, gd = {0.0f, 0.0f};
        GATHER_MAIN(gc, W2);
        GATHER_MAIN(gd, W3);
        GATHER_TAIL(gc, cW2, rowC);
        GATHER_TAIL(gd, cW3, rowD);
        {
            int r6 = t + 6; if (r6 > T_STEPS - 1) r6 = T_STEPS - 1;
            int r7 = t + 7; if (r7 > T_STEPS - 1) r7 = T_STEPS - 1;
            LOADSET(cW2, W2, r6 * BATCH + b);
            LOADSET(cW3, W3, r7 * BATCH + b);
        }
        SCANSTEP(gc, rowC);
        SCANSTEP(gd, rowD);
    }
#undef LOADSET
#undef GCHUNK4
#undef GATHER_MAIN
#undef GTCHUNK
#undef GATHER_TAIL
#undef SCANSTEP
}

// DPP partial-sum ladder step: pure VALU (backend folds into v_add_f32_dpp).
#define DPP_TERM(X, CTRL) \
    __int_as_float(__builtin_amdgcn_update_dpp(0, __float_as_int(X), CTRL, 0xF, 0xF, true))

// ---------------- Kernel 34: output synapse + LI scan, 8-way t-split (r13 verbatim) ----------------
__global__ __launch_bounds__(256) void k_li(const uint32_t* __restrict__ zmask,
                                            const float* __restrict__ w_o,
                                            float* __restrict__ out,
                                            float2* __restrict__ svbuf) {
    extern __shared__ __align__(16) float wo4[];  // 1152 slots * 16 B = 18,432 B
    const int gb  = blockIdx.x;                   // seg(8) x bquad(32) x oct(8)
    const int seg = gb >> 8;
    const int rem = gb & 255;
    const int bq  = rem >> 3;
    const int oct = rem & 7;
    const int o0  = oct << 2;
    const int tid = threadIdx.x;

    for (int lin = tid; lin < 4096; lin += 256) {
        int o = lin & 3, idx = lin >> 2;
        int h = ((idx >> 6) << 6) + ((idx & 31) << 1) + ((idx >> 5) & 1);
        wo4[((idx + (idx >> 3)) << 2) + o] = w_o[(size_t)(o0 + o) * N_H + h];
    }
    __syncthreads();

    const int b    = (bq << 2) + (tid >> 6);      // one b per wave
    const int l    = tid & 63;
    const int word = l & 31;
    const int tofs = l >> 5;                      // half A: t, half B: t+1
    const uint32_t baseoff = (uint32_t)(576 * word);   // (36*word)*16 bytes
    const char* wbase = (const char*)wo4 + baseoff;
    const int t0 = seg << 6, t1 = t0 + 64;        // 64-step segment

    float s0 = 0, s1 = 0, s2 = 0, s3 = 0;
    float v0 = 0, v1 = 0, v2 = 0, v3 = 0;

    uint32_t mcur = zmask[(uint32_t)((t0 + tofs) * BATCH + b) * 32 + word];
    for (int t = t0; t < t1; t += 2) {
        uint32_t ma = mcur;
        int tp = t + 2; if (tp >= t1) tp = t0;    // dummy prefetch on last pair
        mcur = zmask[(uint32_t)((tp + tofs) * BATCH + b) * 32 + word];

        float a0 = 0.0f, a1 = 0.0f, a2 = 0.0f, a3 = 0.0f;
        while (ma) {
            int j = __builtin_ctz(ma); ma &= ma - 1;
            const float4 wv = *(const float4*)(wbase + (((j + (j >> 3)) << 4)));
            a0 += wv.x; a1 += wv.y; a2 += wv.z; a3 += wv.w;
        }

        a0 += DPP_TERM(a0, 0x111); a1 += DPP_TERM(a1, 0x111);
        a2 += DPP_TERM(a2, 0x111); a3 += DPP_TERM(a3, 0x111);
        a0 += DPP_TERM(a0, 0x112); a1 += DPP_TERM(a1, 0x112);
        a2 += DPP_TERM(a2, 0x112); a3 += DPP_TERM(a3, 0x112);
        a0 += DPP_TERM(a0, 0x114); a1 += DPP_TERM(a1, 0x114);
        a2 += DPP_TERM(a2, 0x114); a3 += DPP_TERM(a3, 0x114);
        a0 += DPP_TERM(a0, 0x118); a1 += DPP_TERM(a1, 0x118);
        a2 += DPP_TERM(a2, 0x118); a3 += DPP_TERM(a3, 0x118);
        a0 += DPP_TERM(a0, 0x142); a1 += DPP_TERM(a1, 0x142);
        a2 += DPP_TERM(a2, 0x142); a3 += DPP_TERM(a3, 0x142);

        float b0 = xpick(a0), b1 = xpick(a1), b2 = xpick(a2), b3 = xpick(a3);

        s0 = __builtin_fmaf(s0, 0.875f, a0); v0 = __builtin_fmaf(0.125f, s0 - v0, v0);
        s1 = __builtin_fmaf(s1, 0.875f, a1); v1 = __builtin_fmaf(0.125f, s1 - v1, v1);
        s2 = __builtin_fmaf(s2, 0.875f, a2); v2 = __builtin_fmaf(0.125f, s2 - v2, v2);
        s3 = __builtin_fmaf(s3, 0.875f, a3); v3 = __builtin_fmaf(0.125f, s3 - v3, v3);
        if (l == 31)
            *(float4*)(out + (size_t)(t * BATCH + b) * 32 + o0) =
                make_float4(v0, v1, v2, v3);

        s0 = __builtin_fmaf(s0, 0.875f, b0); v0 = __builtin_fmaf(0.125f, s0 - v0, v0);
        s1 = __builtin_fmaf(s1, 0.875f, b1); v1 = __builtin_fmaf(0.125f, s1 - v1, v1);
        s2 = __builtin_fmaf(s2, 0.875f, b2); v2 = __builtin_fmaf(0.125f, s2 - v2, v2);
        s3 = __builtin_fmaf(s3, 0.875f, b3); v3 = __builtin_fmaf(0.125f, s3 - v3, v3);
        if (l == 31)
            *(float4*)(out + (size_t)((t + 1) * BATCH + b) * 32 + o0) =
                make_float4(v0, v1, v2, v3);
    }
    if (l == 31) {                        // zero-run end state of this segment
        float2* sp = svbuf + ((size_t)seg * BATCH + b) * 32 + o0;
        sp[0] = make_float2(s0, v0);
        sp[1] = make_float2(s1, v1);
        sp[2] = make_float2(s2, v2);
        sp[3] = make_float2(s3, v3);
    }
}

// ---------------- Kernel F: homogeneous LI correction for segs 1..7 (r13 verbatim) ----------------
__global__ __launch_bounds__(256) void k_fix(const float2* __restrict__ svbuf,
                                             float* __restrict__ out) {
    int idx = blockIdx.x * 256 + threadIdx.x;     // 448*128*32 elements
    int o = idx & 31;
    int r = idx >> 5;
    int b = r & 127;
    int t = 64 + (r >> 7);                        // t in [64, 512)
    int seg = t >> 6;                             // 1..7
    int k = (t & 63) + 1;                         // 1..64
    const float A64 = 1.9431852e-4f;              // 0.875^64
    const float C64 = 1.5545481e-3f;              // 0.125*64*A64
    float2 S = svbuf[(size_t)b * 32 + o];         // seg-0 zero-run end state
    for (int q = 1; q < seg; ++q) {               // uniform trip count per block
        float2 z = svbuf[((size_t)q * BATCH + b) * 32 + o];
        S = make_float2(z.x + A64 * S.x, z.y + A64 * S.y + C64 * S.x);
    }
    float ak = exp2f((float)k * -0.19264508f);    // 0.875^k
    float corr = __builtin_fmaf(ak, S.y, 0.125f * (float)k * ak * S.x);
    out[(size_t)(t * BATCH + b) * 32 + o] += corr;
}

// ---------------- launch ----------------
extern "C" void kernel_launch(void* const* d_in, const int* in_sizes, int n_in,
                              void* d_out, int out_size, void* d_ws, size_t ws_size,
                              hipStream_t stream) {
    const float* spikes = (const float*)d_in[0];
    const float* w_h    = (const float*)d_in[1];
    const float* w_o    = (const float*)d_in[2];
    float* out = (float*)d_out;

    char* ws = (char*)d_ws;
    uint32_t* pm    = (uint32_t*)(ws);                 //  8,388,608
    uint16_t* pt    = (uint16_t*)(ws + 8388608);       //  4,194,304
    uint32_t* cnts  = (uint32_t*)(ws + 12582912);      //    262,144
    float*    w_t   = (float*)   (ws + 12845056);      //  1,048,576
    uint32_t* zmask = (uint32_t*)(ws + 13893632);      //  8,388,608
    float2*   svbuf = (float2*)  (ws);                 //    262,144 (reuses pm;
                                                       //    ordered after k_lif)

    const int lds12 = (256 * 64 + 64) * 4;   // 65,792 B -> 2 blocks/CU
    const int lds34 = 1152 * 16;             // 18,432 B -> 8 blocks/CU
    hipFuncSetAttribute((const void*)k_lif, hipFuncAttributeMaxDynamicSharedMemorySize, lds12);
    hipFuncSetAttribute((const void*)k_li,  hipFuncAttributeMaxDynamicSharedMemorySize, lds34);

    k_prep<<<(T_STEPS * BATCH) / 16, 256, 0, stream>>>(spikes, w_h, w_t, pm, pt, cnts);
    k_lif<<<512, 256, lds12, stream>>>(pm, pt, cnts, w_t, zmask);
    k_li<<<8 * 32 * 8, 256, lds34, stream>>>(zmask, w_o, out, svbuf);
    k_fix<<<(448 * BATCH * N_OUT) / 256, 256, 0, stream>>>(svbuf, out);
}